// Round 1
// baseline (3041.365 us; speedup 1.0000x reference)
//
#include <hip/hip_runtime.h>
#include <math.h>

#define D 128

// ---------------------------------------------------------------------------
// Scatter edge messages: agg[dst] += x[src] * rel[etype]; deg[dst] += 1
// One thread per (edge, 4 consecutive dims): E*32 threads.
// ---------------------------------------------------------------------------
__global__ void scatter_msgs(const float* __restrict__ x,
                             const float* __restrict__ rel,
                             const int* __restrict__ src,
                             const int* __restrict__ dst,
                             const int* __restrict__ etype,
                             float* __restrict__ agg,
                             float* __restrict__ deg,   // nullable
                             int E) {
    int gid = blockIdx.x * blockDim.x + threadIdx.x;
    int e = gid >> 5;
    if (e >= E) return;
    int lane = gid & 31;
    int c4 = lane << 2;
    int s = src[e], dd = dst[e], t = etype[e];
    float4 xv = *(const float4*)(x + (size_t)s * D + c4);
    float4 rv = *(const float4*)(rel + (size_t)t * D + c4);
    float* ap = agg + (size_t)dd * D + c4;
    atomicAdd(ap + 0, xv.x * rv.x);
    atomicAdd(ap + 1, xv.y * rv.y);
    atomicAdd(ap + 2, xv.z * rv.z);
    atomicAdd(ap + 3, xv.w * rv.w);
    if (deg != nullptr && lane == 0) atomicAdd(deg + dd, 1.0f);
}

// ---------------------------------------------------------------------------
// Jump diffusion scatter: out[jdst] += jump_weight * edge_w[e] * emb[jsrc]
// ---------------------------------------------------------------------------
__global__ void scatter_jump(const float* __restrict__ emb,
                             const float* __restrict__ ew,
                             const float* __restrict__ jwp,
                             const int* __restrict__ jsrc,
                             const int* __restrict__ jdst,
                             float* __restrict__ out,
                             int EJ) {
    int gid = blockIdx.x * blockDim.x + threadIdx.x;
    int e = gid >> 5;
    if (e >= EJ) return;
    int lane = gid & 31;
    int c4 = lane << 2;
    float w = jwp[0] * ew[e];
    int s = jsrc[e], dd = jdst[e];
    float4 xv = *(const float4*)(emb + (size_t)s * D + c4);
    float* op = out + (size_t)dd * D + c4;
    atomicAdd(op + 0, w * xv.x);
    atomicAdd(op + 1, w * xv.y);
    atomicAdd(op + 2, w * xv.z);
    atomicAdd(op + 3, w * xv.w);
}

// ---------------------------------------------------------------------------
// deg -> 1/max(deg,1) in place
// ---------------------------------------------------------------------------
__global__ void deg_finalize(float* __restrict__ deg, int N) {
    int i = blockIdx.x * blockDim.x + threadIdx.x;
    if (i < N) deg[i] = 1.0f / fmaxf(deg[i], 1.0f);
}

// ---------------------------------------------------------------------------
// Fused: out[row] = x[row] + res * tanh( (agg[row]*dinv[row]) @ W + x @ Wl )
//                 (+ addin[row] if addin != null)
// Tile: 32 rows x 128 cols per block of 256 threads.
// Thread tile: 4 rows x 4 cols. x/agg rows staged in LDS, W from L2.
// ---------------------------------------------------------------------------
__launch_bounds__(256, 2)
__global__ void fused_gemm(const float* __restrict__ x,
                           const float* __restrict__ agg,
                           const float* __restrict__ dinv,
                           const float* __restrict__ W,
                           const float* __restrict__ Wl,
                           const float* __restrict__ resp,
                           const float* __restrict__ addin,  // nullable
                           float* __restrict__ out,
                           int N) {
    __shared__ float xs[32 * D];
    __shared__ float as[32 * D];
    int tid = threadIdx.x;
    int row0 = blockIdx.x * 32;

    // stage 32 rows of x and agg*dinv into LDS (float4 granularity)
    for (int i = tid; i < 32 * (D / 4); i += 256) {
        int r = i >> 5;        // D/4 = 32 float4 per row
        int cq = i & 31;
        int row = row0 + r;
        float4 xv = make_float4(0.f, 0.f, 0.f, 0.f);
        float4 av = make_float4(0.f, 0.f, 0.f, 0.f);
        if (row < N) {
            xv = *(const float4*)(x + (size_t)row * D + cq * 4);
            av = *(const float4*)(agg + (size_t)row * D + cq * 4);
            float di = dinv[row];
            av.x *= di; av.y *= di; av.z *= di; av.w *= di;
        }
        *(float4*)(xs + r * D + cq * 4) = xv;
        *(float4*)(as + r * D + cq * 4) = av;
    }
    __syncthreads();

    int cg = tid & 31;      // column group: 32 groups of 4 cols
    int rg = tid >> 5;      // row group: 8 groups of 4 rows
    int col = cg * 4;
    int rbase = rg * 4;

    float4 acc[4];
#pragma unroll
    for (int r = 0; r < 4; r++) acc[r] = make_float4(0.f, 0.f, 0.f, 0.f);

    for (int k = 0; k < D; k += 4) {
        float4 w[4], wl[4];
#pragma unroll
        for (int kk = 0; kk < 4; kk++) {
            w[kk]  = *(const float4*)(W  + (size_t)(k + kk) * D + col);
            wl[kk] = *(const float4*)(Wl + (size_t)(k + kk) * D + col);
        }
#pragma unroll
        for (int r = 0; r < 4; r++) {
            float4 xv = *(const float4*)(xs + (rbase + r) * D + k);
            float4 av = *(const float4*)(as + (rbase + r) * D + k);
            const float* xp = (const float*)&xv;
            const float* ap = (const float*)&av;
#pragma unroll
            for (int kk = 0; kk < 4; kk++) {
                acc[r].x += ap[kk] * w[kk].x + xp[kk] * wl[kk].x;
                acc[r].y += ap[kk] * w[kk].y + xp[kk] * wl[kk].y;
                acc[r].z += ap[kk] * w[kk].z + xp[kk] * wl[kk].z;
                acc[r].w += ap[kk] * w[kk].w + xp[kk] * wl[kk].w;
            }
        }
    }

    float res = resp[0];
#pragma unroll
    for (int r = 0; r < 4; r++) {
        int row = row0 + rbase + r;
        if (row >= N) continue;
        float4 xv = *(const float4*)(xs + (rbase + r) * D + col);
        float4 o;
        o.x = xv.x + res * tanhf(acc[r].x);
        o.y = xv.y + res * tanhf(acc[r].y);
        o.z = xv.z + res * tanhf(acc[r].z);
        o.w = xv.w + res * tanhf(acc[r].w);
        if (addin != nullptr) {
            float4 aj = *(const float4*)(addin + (size_t)row * D + col);
            o.x += aj.x; o.y += aj.y; o.z += aj.z; o.w += aj.w;
        }
        *(float4*)(out + (size_t)row * D + col) = o;
    }
}

extern "C" void kernel_launch(void* const* d_in, const int* in_sizes, int n_in,
                              void* d_out, int out_size, void* d_ws, size_t ws_size,
                              hipStream_t stream) {
    const float* emb    = (const float*)d_in[0];
    const float* change = (const float*)d_in[1];
    const float* W1     = (const float*)d_in[2];
    const float* Wl1    = (const float*)d_in[3];
    const float* rel1   = (const float*)d_in[4];
    const float* W2     = (const float*)d_in[5];
    const float* Wl2    = (const float*)d_in[6];
    const float* rel2   = (const float*)d_in[7];
    const float* res    = (const float*)d_in[8];
    const float* jw     = (const float*)d_in[9];
    const float* ewj    = (const float*)d_in[10];
    const int*   eidx   = (const int*)d_in[11];
    const int*   etype  = (const int*)d_in[12];
    const int*   ejmp   = (const int*)d_in[13];

    const int ND = in_sizes[0];
    const int N  = ND / D;
    const int E  = in_sizes[12];
    const int EJ = in_sizes[10];

    float* out = (float*)d_out;              // change passthrough
    float* dch = out + (size_t)ND;           // dchange
    float* aggb = (float*)d_ws;              // [N*D]
    float* h1   = aggb + (size_t)ND;         // [N*D]
    float* deg  = h1 + (size_t)ND;           // [N]

    hipMemsetAsync(aggb, 0, (size_t)ND * sizeof(float), stream);
    hipMemsetAsync(deg, 0, (size_t)N * sizeof(float), stream);
    hipMemsetAsync(dch, 0, (size_t)ND * sizeof(float), stream);
    hipMemcpyAsync(out, change, (size_t)ND * sizeof(float),
                   hipMemcpyDeviceToDevice, stream);

    const int threads = 256;
    int sb = (E * 32 + threads - 1) / threads;
    int jb = (EJ * 32 + threads - 1) / threads;
    int gb = (N + 31) / 32;

    // Layer 1 scatter (+deg), deg finalize, jump scatter (into dch)
    scatter_msgs<<<sb, threads, 0, stream>>>(emb, rel1, eidx, eidx + E, etype,
                                             aggb, deg, E);
    deg_finalize<<<(N + 255) / 256, 256, 0, stream>>>(deg, N);
    scatter_jump<<<jb, threads, 0, stream>>>(emb, ewj, jw, ejmp, ejmp + EJ,
                                             dch, EJ);

    // h1 = emb + res*tanh(aggn@W1 + emb@Wl1)
    fused_gemm<<<gb, 256, 0, stream>>>(emb, aggb, deg, W1, Wl1, res, nullptr,
                                       h1, N);

    // Layer 2 scatter (reuse agg buffer)
    hipMemsetAsync(aggb, 0, (size_t)ND * sizeof(float), stream);
    scatter_msgs<<<sb, threads, 0, stream>>>(h1, rel2, eidx, eidx + E, etype,
                                             aggb, nullptr, E);

    // dchange = h1 + res*tanh(aggn@W2 + h1@Wl2) + jump (already in dch)
    fused_gemm<<<gb, 256, 0, stream>>>(h1, aggb, deg, W2, Wl2, res, dch,
                                       dch, N);
}

// Round 2
// 779.807 us; speedup vs baseline: 3.9002x; 3.9002x over previous
//
#include <hip/hip_runtime.h>
#include <math.h>

#define D 128

// ===========================================================================
// CSR build: histogram -> 3-kernel exclusive scan -> bucket fill
// ===========================================================================
__global__ void hist_kernel(const int* __restrict__ dst, int* __restrict__ cnt,
                            int E) {
    int e = blockIdx.x * blockDim.x + threadIdx.x;
    if (e < E) atomicAdd(&cnt[dst[e]], 1);
}

// Block scans 1024 elements (256 thr x 4). Writes exclusive offsets + block sum.
__global__ void scan1(const int* __restrict__ cnt, int* __restrict__ offs,
                      int* __restrict__ bsum, int N) {
    __shared__ int sh[256];
    int t = threadIdx.x;
    int base = blockIdx.x * 1024 + t * 4;
    int v0 = 0, v1 = 0, v2 = 0, v3 = 0;
    if (base + 0 < N) v0 = cnt[base + 0];
    if (base + 1 < N) v1 = cnt[base + 1];
    if (base + 2 < N) v2 = cnt[base + 2];
    if (base + 3 < N) v3 = cnt[base + 3];
    int tsum = v0 + v1 + v2 + v3;
    sh[t] = tsum;
    __syncthreads();
    for (int off = 1; off < 256; off <<= 1) {
        int x = (t >= off) ? sh[t - off] : 0;
        __syncthreads();
        sh[t] += x;
        __syncthreads();
    }
    int excl = sh[t] - tsum;
    if (base + 0 < N) offs[base + 0] = excl;
    excl += v0;
    if (base + 1 < N) offs[base + 1] = excl;
    excl += v1;
    if (base + 2 < N) offs[base + 2] = excl;
    excl += v2;
    if (base + 3 < N) offs[base + 3] = excl;
    if (t == 255) bsum[blockIdx.x] = sh[255];
}

// Single block: exclusive scan of block sums in place (NB <= 256).
__global__ void scan2(int* __restrict__ bsum, int NB) {
    __shared__ int sh[256];
    int t = threadIdx.x;
    int v = (t < NB) ? bsum[t] : 0;
    sh[t] = v;
    __syncthreads();
    for (int off = 1; off < 256; off <<= 1) {
        int x = (t >= off) ? sh[t - off] : 0;
        __syncthreads();
        sh[t] += x;
        __syncthreads();
    }
    if (t < NB) bsum[t] = sh[t] - v;
}

// Add block bases; init fill cursor.
__global__ void scan3(int* __restrict__ offs, const int* __restrict__ bsum,
                      int* __restrict__ cur, int N) {
    int i = blockIdx.x * blockDim.x + threadIdx.x;
    if (i < N) {
        int o = offs[i] + bsum[i >> 10];
        offs[i] = o;
        cur[i] = o;
    }
}

__global__ void fill_conv(const int* __restrict__ src, const int* __restrict__ dst,
                          const int* __restrict__ et, int* __restrict__ cur,
                          int2* __restrict__ pairs, int E) {
    int e = blockIdx.x * blockDim.x + threadIdx.x;
    if (e >= E) return;
    int p = atomicAdd(&cur[dst[e]], 1);
    pairs[p] = make_int2(src[e], et[e]);
}

__global__ void fill_jump(const int* __restrict__ src, const int* __restrict__ dst,
                          const float* __restrict__ ew, int* __restrict__ cur,
                          int2* __restrict__ pairs, int EJ) {
    int e = blockIdx.x * blockDim.x + threadIdx.x;
    if (e >= EJ) return;
    int p = atomicAdd(&cur[dst[e]], 1);
    pairs[p] = make_int2(src[e], __float_as_int(ew[e]));
}

// ===========================================================================
// Gather aggregation: one wave (64 lanes, 2 floats/lane) per destination node.
// agg[n] = (1/max(deg,1)) * sum_{e in CSR[n]} x[src_e] * rel[etype_e]
// ===========================================================================
__global__ void gather_conv(const float* __restrict__ x,
                            const float* __restrict__ rel,
                            const int* __restrict__ offs,
                            const int* __restrict__ cnt,
                            const int2* __restrict__ pairs,
                            float* __restrict__ agg, int N) {
    int node = blockIdx.x * 4 + (threadIdx.x >> 6);
    if (node >= N) return;
    int c = (threadIdx.x & 63) * 2;
    int beg = offs[node], num = cnt[node];
    float2 acc = make_float2(0.f, 0.f);
    for (int i = 0; i < num; i++) {
        int2 pe = pairs[beg + i];
        float2 xv = *(const float2*)(x + (size_t)pe.x * D + c);
        float2 rv = *(const float2*)(rel + (size_t)pe.y * D + c);
        acc.x += xv.x * rv.x;
        acc.y += xv.y * rv.y;
    }
    float dinv = 1.0f / fmaxf((float)num, 1.0f);
    *(float2*)(agg + (size_t)node * D + c) = make_float2(acc.x * dinv, acc.y * dinv);
}

// out[n] = jump_weight * sum_{e} ew_e * emb[src_e]   (writes every row; no memset)
__global__ void gather_jump(const float* __restrict__ emb,
                            const float* __restrict__ jwp,
                            const int* __restrict__ offs,
                            const int* __restrict__ cnt,
                            const int2* __restrict__ pairs,
                            float* __restrict__ out, int N) {
    int node = blockIdx.x * 4 + (threadIdx.x >> 6);
    if (node >= N) return;
    int c = (threadIdx.x & 63) * 2;
    int beg = offs[node], num = cnt[node];
    float2 acc = make_float2(0.f, 0.f);
    for (int i = 0; i < num; i++) {
        int2 pe = pairs[beg + i];
        float w = __int_as_float(pe.y);
        float2 xv = *(const float2*)(emb + (size_t)pe.x * D + c);
        acc.x += w * xv.x;
        acc.y += w * xv.y;
    }
    float jw = jwp[0];
    *(float2*)(out + (size_t)node * D + c) = make_float2(jw * acc.x, jw * acc.y);
}

// ===========================================================================
// Fused: out[row] = x[row] + res * tanh( agg[row] @ W + x[row] @ Wl ) (+addin)
// 32 rows x 128 cols per block of 256 threads; 4x4 per-thread tile.
// ===========================================================================
__launch_bounds__(256, 2)
__global__ void fused_gemm(const float* __restrict__ x,
                           const float* __restrict__ agg,
                           const float* __restrict__ W,
                           const float* __restrict__ Wl,
                           const float* __restrict__ resp,
                           const float* __restrict__ addin,  // nullable
                           float* __restrict__ out,
                           int N) {
    __shared__ float xs[32 * D];
    __shared__ float as[32 * D];
    int tid = threadIdx.x;
    int row0 = blockIdx.x * 32;

    for (int i = tid; i < 32 * (D / 4); i += 256) {
        int r = i >> 5;
        int cq = i & 31;
        int row = row0 + r;
        float4 xv = make_float4(0.f, 0.f, 0.f, 0.f);
        float4 av = make_float4(0.f, 0.f, 0.f, 0.f);
        if (row < N) {
            xv = *(const float4*)(x + (size_t)row * D + cq * 4);
            av = *(const float4*)(agg + (size_t)row * D + cq * 4);
        }
        *(float4*)(xs + r * D + cq * 4) = xv;
        *(float4*)(as + r * D + cq * 4) = av;
    }
    __syncthreads();

    int cg = tid & 31;
    int rg = tid >> 5;
    int col = cg * 4;
    int rbase = rg * 4;

    float4 acc[4];
#pragma unroll
    for (int r = 0; r < 4; r++) acc[r] = make_float4(0.f, 0.f, 0.f, 0.f);

    for (int k = 0; k < D; k += 4) {
        float4 w[4], wl[4];
#pragma unroll
        for (int kk = 0; kk < 4; kk++) {
            w[kk]  = *(const float4*)(W  + (size_t)(k + kk) * D + col);
            wl[kk] = *(const float4*)(Wl + (size_t)(k + kk) * D + col);
        }
#pragma unroll
        for (int r = 0; r < 4; r++) {
            float4 xv = *(const float4*)(xs + (rbase + r) * D + k);
            float4 av = *(const float4*)(as + (rbase + r) * D + k);
            const float* xp = (const float*)&xv;
            const float* ap = (const float*)&av;
#pragma unroll
            for (int kk = 0; kk < 4; kk++) {
                acc[r].x += ap[kk] * w[kk].x + xp[kk] * wl[kk].x;
                acc[r].y += ap[kk] * w[kk].y + xp[kk] * wl[kk].y;
                acc[r].z += ap[kk] * w[kk].z + xp[kk] * wl[kk].z;
                acc[r].w += ap[kk] * w[kk].w + xp[kk] * wl[kk].w;
            }
        }
    }

    float res = resp[0];
#pragma unroll
    for (int r = 0; r < 4; r++) {
        int row = row0 + rbase + r;
        if (row >= N) continue;
        float4 xv = *(const float4*)(xs + (rbase + r) * D + col);
        float4 o;
        o.x = xv.x + res * tanhf(acc[r].x);
        o.y = xv.y + res * tanhf(acc[r].y);
        o.z = xv.z + res * tanhf(acc[r].z);
        o.w = xv.w + res * tanhf(acc[r].w);
        if (addin != nullptr) {
            float4 aj = *(const float4*)(addin + (size_t)row * D + col);
            o.x += aj.x; o.y += aj.y; o.z += aj.z; o.w += aj.w;
        }
        *(float4*)(out + (size_t)row * D + col) = o;
    }
}

extern "C" void kernel_launch(void* const* d_in, const int* in_sizes, int n_in,
                              void* d_out, int out_size, void* d_ws, size_t ws_size,
                              hipStream_t stream) {
    const float* emb    = (const float*)d_in[0];
    const float* change = (const float*)d_in[1];
    const float* W1     = (const float*)d_in[2];
    const float* Wl1    = (const float*)d_in[3];
    const float* rel1   = (const float*)d_in[4];
    const float* W2     = (const float*)d_in[5];
    const float* Wl2    = (const float*)d_in[6];
    const float* rel2   = (const float*)d_in[7];
    const float* res    = (const float*)d_in[8];
    const float* jw     = (const float*)d_in[9];
    const float* ewj    = (const float*)d_in[10];
    const int*   eidx   = (const int*)d_in[11];
    const int*   etype  = (const int*)d_in[12];
    const int*   ejmp   = (const int*)d_in[13];

    const int ND = in_sizes[0];
    const int N  = ND / D;
    const int E  = in_sizes[12];
    const int EJ = in_sizes[10];

    float* out = (float*)d_out;          // change passthrough
    float* dch = out + (size_t)ND;       // dchange

    // workspace layout
    char* w = (char*)d_ws;
    float* aggb   = (float*)w;                 w += (size_t)ND * 4;
    float* h1     = (float*)w;                 w += (size_t)ND * 4;
    int* cnt_e    = (int*)w;                   w += (size_t)N * 4;
    int* offs_e   = (int*)w;                   w += (size_t)N * 4;
    int* cur_e    = (int*)w;                   w += (size_t)N * 4;
    int* cnt_j    = (int*)w;                   w += (size_t)N * 4;
    int* offs_j   = (int*)w;                   w += (size_t)N * 4;
    int* cur_j    = (int*)w;                   w += (size_t)N * 4;
    int* bsum_e   = (int*)w;                   w += 256 * 4;
    int* bsum_j   = (int*)w;                   w += 256 * 4;
    int2* pairs_e = (int2*)w;                  w += (size_t)E * 8;
    int2* pairs_j = (int2*)w;                  w += (size_t)EJ * 8;

    const int T = 256;
    const int NB = (N + 1023) / 1024;

    hipMemsetAsync(cnt_e, 0, (size_t)N * sizeof(int), stream);
    hipMemsetAsync(cnt_j, 0, (size_t)N * sizeof(int), stream);
    hipMemcpyAsync(out, change, (size_t)ND * sizeof(float),
                   hipMemcpyDeviceToDevice, stream);

    // ---- build conv CSR (shared by both layers: same dst) ----
    hist_kernel<<<(E + T - 1) / T, T, 0, stream>>>(eidx + E, cnt_e, E);
    scan1<<<NB, 256, 0, stream>>>(cnt_e, offs_e, bsum_e, N);
    scan2<<<1, 256, 0, stream>>>(bsum_e, NB);
    scan3<<<(N + T - 1) / T, T, 0, stream>>>(offs_e, bsum_e, cur_e, N);
    fill_conv<<<(E + T - 1) / T, T, 0, stream>>>(eidx, eidx + E, etype, cur_e,
                                                 pairs_e, E);

    // ---- build jump CSR ----
    hist_kernel<<<(EJ + T - 1) / T, T, 0, stream>>>(ejmp + EJ, cnt_j, EJ);
    scan1<<<NB, 256, 0, stream>>>(cnt_j, offs_j, bsum_j, N);
    scan2<<<1, 256, 0, stream>>>(bsum_j, NB);
    scan3<<<(N + T - 1) / T, T, 0, stream>>>(offs_j, bsum_j, cur_j, N);
    fill_jump<<<(EJ + T - 1) / T, T, 0, stream>>>(ejmp, ejmp + EJ, ewj, cur_j,
                                                  pairs_j, EJ);

    int gatherB = (N + 3) / 4;   // 4 nodes (waves) per 256-thread block
    int gemmB   = (N + 31) / 32;

    // ---- layer 1 ----
    gather_conv<<<gatherB, 256, 0, stream>>>(emb, rel1, offs_e, cnt_e, pairs_e,
                                             aggb, N);
    fused_gemm<<<gemmB, 256, 0, stream>>>(emb, aggb, W1, Wl1, res, nullptr,
                                          h1, N);

    // ---- jump diffusion into dch (writes every row) ----
    gather_jump<<<gatherB, 256, 0, stream>>>(emb, jw, offs_j, cnt_j, pairs_j,
                                             dch, N);

    // ---- layer 2 ----
    gather_conv<<<gatherB, 256, 0, stream>>>(h1, rel2, offs_e, cnt_e, pairs_e,
                                             aggb, N);
    fused_gemm<<<gemmB, 256, 0, stream>>>(h1, aggb, W2, Wl2, res, dch,
                                          dch, N);
}

// Round 3
// 641.580 us; speedup vs baseline: 4.7404x; 1.2154x over previous
//
#include <hip/hip_runtime.h>
#include <math.h>

#define D 128

typedef __attribute__((ext_vector_type(8))) short short8v;   // 8 bf16 = 4 VGPR
typedef __attribute__((ext_vector_type(4))) float f32x4;     // MFMA acc

__device__ inline short f2bf(float f) {                      // RNE fp32->bf16
    unsigned u = __float_as_uint(f);
    u += 0x7FFF + ((u >> 16) & 1);
    return (short)(u >> 16);
}

// ===========================================================================
// CSR build: histogram -> 3-kernel exclusive scan -> bucket fill
// ===========================================================================
__global__ void hist_kernel(const int* __restrict__ dst, int* __restrict__ cnt,
                            int E) {
    int e = blockIdx.x * blockDim.x + threadIdx.x;
    if (e < E) atomicAdd(&cnt[dst[e]], 1);
}

__global__ void scan1(const int* __restrict__ cnt, int* __restrict__ offs,
                      int* __restrict__ bsum, int N) {
    __shared__ int sh[256];
    int t = threadIdx.x;
    int base = blockIdx.x * 1024 + t * 4;
    int v0 = 0, v1 = 0, v2 = 0, v3 = 0;
    if (base + 0 < N) v0 = cnt[base + 0];
    if (base + 1 < N) v1 = cnt[base + 1];
    if (base + 2 < N) v2 = cnt[base + 2];
    if (base + 3 < N) v3 = cnt[base + 3];
    int tsum = v0 + v1 + v2 + v3;
    sh[t] = tsum;
    __syncthreads();
    for (int off = 1; off < 256; off <<= 1) {
        int x = (t >= off) ? sh[t - off] : 0;
        __syncthreads();
        sh[t] += x;
        __syncthreads();
    }
    int excl = sh[t] - tsum;
    if (base + 0 < N) offs[base + 0] = excl;
    excl += v0;
    if (base + 1 < N) offs[base + 1] = excl;
    excl += v1;
    if (base + 2 < N) offs[base + 2] = excl;
    excl += v2;
    if (base + 3 < N) offs[base + 3] = excl;
    if (t == 255) bsum[blockIdx.x] = sh[255];
}

__global__ void scan2(int* __restrict__ bsum, int NB) {
    __shared__ int sh[256];
    int t = threadIdx.x;
    int v = (t < NB) ? bsum[t] : 0;
    sh[t] = v;
    __syncthreads();
    for (int off = 1; off < 256; off <<= 1) {
        int x = (t >= off) ? sh[t - off] : 0;
        __syncthreads();
        sh[t] += x;
        __syncthreads();
    }
    if (t < NB) bsum[t] = sh[t] - v;
}

__global__ void scan3(int* __restrict__ offs, const int* __restrict__ bsum,
                      int* __restrict__ cur, int N) {
    int i = blockIdx.x * blockDim.x + threadIdx.x;
    if (i < N) {
        int o = offs[i] + bsum[i >> 10];
        offs[i] = o;
        cur[i] = o;
    }
}

__global__ void fill_conv(const int* __restrict__ src, const int* __restrict__ dst,
                          const int* __restrict__ et, int* __restrict__ cur,
                          int2* __restrict__ pairs, int E) {
    int e = blockIdx.x * blockDim.x + threadIdx.x;
    if (e >= E) return;
    int p = atomicAdd(&cur[dst[e]], 1);
    pairs[p] = make_int2(src[e], et[e]);
}

__global__ void fill_jump(const int* __restrict__ src, const int* __restrict__ dst,
                          const float* __restrict__ ew, int* __restrict__ cur,
                          int2* __restrict__ pairs, int EJ) {
    int e = blockIdx.x * blockDim.x + threadIdx.x;
    if (e >= EJ) return;
    int p = atomicAdd(&cur[dst[e]], 1);
    pairs[p] = make_int2(src[e], __float_as_int(ew[e]));
}

// ===========================================================================
// Weight pack into MFMA B-fragment lane order (bf16).
// Wstack rows 0..127 = W (agg path), 128..255 = Wl (x path).
// Frag for (tile_n tn, tile_k tk): lane holds B[tk*32 + (lane>>4)*8 + j]
//                                          [tn*16 + (lane&15)], j=0..7 contig.
// ===========================================================================
__global__ void pack_w(const float* __restrict__ W, const float* __restrict__ Wl,
                       short* __restrict__ Bpk) {
    int lane = threadIdx.x;          // 64
    int tile = blockIdx.x;           // 64: tn = tile>>3, tk = tile&7
    int tn = tile >> 3, tk = tile & 7;
    int n = tn * 16 + (lane & 15);
    int k0 = tk * 32 + (lane >> 4) * 8;
    short* o = Bpk + ((size_t)tile * 64 + lane) * 8;
#pragma unroll
    for (int j = 0; j < 8; j++) {
        int k = k0 + j;
        float f = (k < D) ? W[(size_t)k * D + n] : Wl[(size_t)(k - D) * D + n];
        o[j] = f2bf(f);
    }
}

// Convert a [N][128] fp32 matrix into the x-half (cols 128..255) of Abf.
__global__ void cvt_rows(const float* __restrict__ x, short* __restrict__ Abf,
                         int N) {
    int i = blockIdx.x * blockDim.x + threadIdx.x;  // one thread per 4 elems
    int row = i >> 5;
    int c4 = (i & 31) * 4;
    if (row >= N) return;
    float4 v = *(const float4*)(x + (size_t)row * D + c4);
    short4 o;
    o.x = f2bf(v.x); o.y = f2bf(v.y); o.z = f2bf(v.z); o.w = f2bf(v.w);
    *(short4*)(Abf + (size_t)row * 256 + 128 + c4) = o;
}

// ===========================================================================
// Gather aggregation: one wave per node; writes bf16 agg into Abf cols 0..127.
// ===========================================================================
__global__ void gather_conv(const float* __restrict__ x,
                            const float* __restrict__ rel,
                            const int* __restrict__ offs,
                            const int* __restrict__ cnt,
                            const int2* __restrict__ pairs,
                            short* __restrict__ Abf, int N) {
    int node = blockIdx.x * 4 + (threadIdx.x >> 6);
    if (node >= N) return;
    int c = (threadIdx.x & 63) * 2;
    int beg = offs[node], num = cnt[node];
    float2 acc = make_float2(0.f, 0.f);
    for (int i = 0; i < num; i++) {
        int2 pe = pairs[beg + i];
        float2 xv = *(const float2*)(x + (size_t)pe.x * D + c);
        float2 rv = *(const float2*)(rel + (size_t)pe.y * D + c);
        acc.x += xv.x * rv.x;
        acc.y += xv.y * rv.y;
    }
    float dinv = 1.0f / fmaxf((float)num, 1.0f);
    short2 o;
    o.x = f2bf(acc.x * dinv);
    o.y = f2bf(acc.y * dinv);
    *(short2*)(Abf + (size_t)node * 256 + c) = o;
}

// out[n] = jump_weight * sum_e ew_e * emb[src_e]   (writes every row)
__global__ void gather_jump(const float* __restrict__ emb,
                            const float* __restrict__ jwp,
                            const int* __restrict__ offs,
                            const int* __restrict__ cnt,
                            const int2* __restrict__ pairs,
                            float* __restrict__ out, int N) {
    int node = blockIdx.x * 4 + (threadIdx.x >> 6);
    if (node >= N) return;
    int c = (threadIdx.x & 63) * 2;
    int beg = offs[node], num = cnt[node];
    float2 acc = make_float2(0.f, 0.f);
    for (int i = 0; i < num; i++) {
        int2 pe = pairs[beg + i];
        float w = __int_as_float(pe.y);
        float2 xv = *(const float2*)(emb + (size_t)pe.x * D + c);
        acc.x += w * xv.x;
        acc.y += w * xv.y;
    }
    float jw = jwp[0];
    *(float2*)(out + (size_t)node * D + c) = make_float2(jw * acc.x, jw * acc.y);
}

// ===========================================================================
// MFMA GEMM: C = Abf[N][256] @ Bpk(256x128), out = x + res*tanh(C) (+addin)
// Block: 256 thr = 4 waves, tile 64 rows x 128 cols. Wave: 32x64 (2x4 frags).
// No LDS, no barriers: A frags contiguous from Abf, B frags pre-packed.
// ===========================================================================
__launch_bounds__(256)
__global__ void mfma_gemm(const short* __restrict__ Abf,
                          const short* __restrict__ Bpk,
                          const float* __restrict__ x,
                          const float* __restrict__ resp,
                          const float* __restrict__ addin,  // nullable
                          float* __restrict__ out,
                          int N) {
    int w = threadIdx.x >> 6;
    int lane = threadIdx.x & 63;
    int rb = (w & 1) * 32;           // row band within block
    int cb = (w >> 1) * 64;          // col band within block
    int row0 = blockIdx.x * 64;
    int m = lane & 15, quad = lane >> 4;

    f32x4 acc[2][4];
#pragma unroll
    for (int rt = 0; rt < 2; rt++)
#pragma unroll
        for (int ct = 0; ct < 4; ct++) acc[rt][ct] = (f32x4)(0.f);

    const short* arow0 = Abf + (size_t)(row0 + rb + m) * 256 + quad * 8;
    const short* arow1 = arow0 + 16 * 256;
    const short* bbase = Bpk + (((size_t)(cb >> 4)) * 8 * 64 + lane) * 8;

#pragma unroll
    for (int kt = 0; kt < 8; kt++) {
        short8v a0 = *(const short8v*)(arow0 + kt * 32);
        short8v a1 = *(const short8v*)(arow1 + kt * 32);
        short8v b[4];
#pragma unroll
        for (int ct = 0; ct < 4; ct++)
            b[ct] = *(const short8v*)(bbase + ((size_t)(ct * 8 + kt)) * 64 * 8);
#pragma unroll
        for (int ct = 0; ct < 4; ct++) {
            acc[0][ct] = __builtin_amdgcn_mfma_f32_16x16x32_bf16(a0, b[ct],
                                                                 acc[0][ct], 0, 0, 0);
            acc[1][ct] = __builtin_amdgcn_mfma_f32_16x16x32_bf16(a1, b[ct],
                                                                 acc[1][ct], 0, 0, 0);
        }
    }

    float res = resp[0];
#pragma unroll
    for (int rt = 0; rt < 2; rt++) {
#pragma unroll
        for (int ct = 0; ct < 4; ct++) {
            int colg = cb + ct * 16 + m;
#pragma unroll
            for (int r = 0; r < 4; r++) {
                int rowg = row0 + rb + rt * 16 + quad * 4 + r;
                if (rowg >= N) continue;
                size_t idx = (size_t)rowg * D + colg;
                float o = x[idx] + res * tanhf(acc[rt][ct][r]);
                if (addin != nullptr) o += addin[idx];
                out[idx] = o;
            }
        }
    }
}

extern "C" void kernel_launch(void* const* d_in, const int* in_sizes, int n_in,
                              void* d_out, int out_size, void* d_ws, size_t ws_size,
                              hipStream_t stream) {
    const float* emb    = (const float*)d_in[0];
    const float* change = (const float*)d_in[1];
    const float* W1     = (const float*)d_in[2];
    const float* Wl1    = (const float*)d_in[3];
    const float* rel1   = (const float*)d_in[4];
    const float* W2     = (const float*)d_in[5];
    const float* Wl2    = (const float*)d_in[6];
    const float* rel2   = (const float*)d_in[7];
    const float* res    = (const float*)d_in[8];
    const float* jw     = (const float*)d_in[9];
    const float* ewj    = (const float*)d_in[10];
    const int*   eidx   = (const int*)d_in[11];
    const int*   etype  = (const int*)d_in[12];
    const int*   ejmp   = (const int*)d_in[13];

    const int ND = in_sizes[0];
    const int N  = ND / D;
    const int E  = in_sizes[12];
    const int EJ = in_sizes[10];
    const int NP = ((N + 63) / 64) * 64;     // row-padded for 64-row GEMM tiles

    float* out = (float*)d_out;          // change passthrough
    float* dch = out + (size_t)ND;       // dchange

    // workspace layout (Abf first: 16B-aligned)
    char* w = (char*)d_ws;
    short* Abf    = (short*)w;                 w += (size_t)NP * 256 * 2;
    float* h1     = (float*)w;                 w += (size_t)ND * 4;
    short* Bpk1   = (short*)w;                 w += (size_t)64 * 64 * 8 * 2;
    short* Bpk2   = (short*)w;                 w += (size_t)64 * 64 * 8 * 2;
    int* cnt_e    = (int*)w;                   w += (size_t)N * 4;
    int* offs_e   = (int*)w;                   w += (size_t)N * 4;
    int* cur_e    = (int*)w;                   w += (size_t)N * 4;
    int* cnt_j    = (int*)w;                   w += (size_t)N * 4;
    int* offs_j   = (int*)w;                   w += (size_t)N * 4;
    int* cur_j    = (int*)w;                   w += (size_t)N * 4;
    int* bsum_e   = (int*)w;                   w += 256 * 4;
    int* bsum_j   = (int*)w;                   w += 256 * 4;
    int2* pairs_e = (int2*)w;                  w += (size_t)E * 8;
    int2* pairs_j = (int2*)w;                  w += (size_t)EJ * 8;

    const int T = 256;
    const int NB = (N + 1023) / 1024;

    hipMemsetAsync(cnt_e, 0, (size_t)N * sizeof(int), stream);
    hipMemsetAsync(cnt_j, 0, (size_t)N * sizeof(int), stream);
    hipMemcpyAsync(out, change, (size_t)ND * sizeof(float),
                   hipMemcpyDeviceToDevice, stream);

    // ---- build conv CSR (shared by both layers: same dst) ----
    hist_kernel<<<(E + T - 1) / T, T, 0, stream>>>(eidx + E, cnt_e, E);
    scan1<<<NB, 256, 0, stream>>>(cnt_e, offs_e, bsum_e, N);
    scan2<<<1, 256, 0, stream>>>(bsum_e, NB);
    scan3<<<(N + T - 1) / T, T, 0, stream>>>(offs_e, bsum_e, cur_e, N);
    fill_conv<<<(E + T - 1) / T, T, 0, stream>>>(eidx, eidx + E, etype, cur_e,
                                                 pairs_e, E);

    // ---- build jump CSR ----
    hist_kernel<<<(EJ + T - 1) / T, T, 0, stream>>>(ejmp + EJ, cnt_j, EJ);
    scan1<<<NB, 256, 0, stream>>>(cnt_j, offs_j, bsum_j, N);
    scan2<<<1, 256, 0, stream>>>(bsum_j, NB);
    scan3<<<(N + T - 1) / T, T, 0, stream>>>(offs_j, bsum_j, cur_j, N);
    fill_jump<<<(EJ + T - 1) / T, T, 0, stream>>>(ejmp, ejmp + EJ, ewj, cur_j,
                                                  pairs_j, EJ);

    // ---- weight packs (bf16, B-fragment lane order) ----
    pack_w<<<64, 64, 0, stream>>>(W1, Wl1, Bpk1);
    pack_w<<<64, 64, 0, stream>>>(W2, Wl2, Bpk2);

    int gatherB = (N + 3) / 4;
    int cvtB    = (N * 32 + T - 1) / T;
    int gemmB   = NP / 64;

    // ---- layer 1 ----
    cvt_rows<<<cvtB, T, 0, stream>>>(emb, Abf, N);
    gather_conv<<<gatherB, 256, 0, stream>>>(emb, rel1, offs_e, cnt_e, pairs_e,
                                             Abf, N);
    mfma_gemm<<<gemmB, 256, 0, stream>>>(Abf, Bpk1, emb, res, nullptr, h1, N);

    // ---- jump diffusion into dch ----
    gather_jump<<<gatherB, 256, 0, stream>>>(emb, jw, offs_j, cnt_j, pairs_j,
                                             dch, N);

    // ---- layer 2 ----
    cvt_rows<<<cvtB, T, 0, stream>>>(h1, Abf, N);
    gather_conv<<<gatherB, 256, 0, stream>>>(h1, rel2, offs_e, cnt_e, pairs_e,
                                             Abf, N);
    mfma_gemm<<<gemmB, 256, 0, stream>>>(Abf, Bpk2, h1, res, dch, dch, N);
}

// Round 4
// 596.308 us; speedup vs baseline: 5.1003x; 1.0759x over previous
//
#include <hip/hip_runtime.h>
#include <math.h>

#define D 128

typedef __attribute__((ext_vector_type(8))) short short8v;   // 8 bf16 = 4 VGPR
typedef __attribute__((ext_vector_type(4))) float f32x4;     // MFMA acc

__device__ inline short f2bf(float f) {                      // RNE fp32->bf16
    unsigned u = __float_as_uint(f);
    u += 0x7FFF + ((u >> 16) & 1);
    return (short)(u >> 16);
}
__device__ inline float bf2f(unsigned short s) {
    return __uint_as_float(((unsigned)s) << 16);
}

// ===========================================================================
// Concatenated CSR build for conv (dst in [0,N)) and jump (dst in [N,2N)).
// pairs[] holds conv entries in [0,E) and jump entries in [E,E+EJ).
// ===========================================================================
__global__ void hist_both(const int* __restrict__ dst_e,
                          const int* __restrict__ dst_j,
                          int* __restrict__ cnt, int E, int EJ, int N) {
    int i = blockIdx.x * blockDim.x + threadIdx.x;
    if (i < E) atomicAdd(&cnt[dst_e[i]], 1);
    else if (i < E + EJ) atomicAdd(&cnt[N + dst_j[i - E]], 1);
}

// Block scans 1024 elements (256 thr x 4). Exclusive offsets + block sum.
__global__ void scan1(const int* __restrict__ cnt, int* __restrict__ offs,
                      int* __restrict__ bsum, int M) {
    __shared__ int sh[256];
    int t = threadIdx.x;
    int base = blockIdx.x * 1024 + t * 4;
    int v0 = 0, v1 = 0, v2 = 0, v3 = 0;
    if (base + 0 < M) v0 = cnt[base + 0];
    if (base + 1 < M) v1 = cnt[base + 1];
    if (base + 2 < M) v2 = cnt[base + 2];
    if (base + 3 < M) v3 = cnt[base + 3];
    int tsum = v0 + v1 + v2 + v3;
    sh[t] = tsum;
    __syncthreads();
    for (int off = 1; off < 256; off <<= 1) {
        int x = (t >= off) ? sh[t - off] : 0;
        __syncthreads();
        sh[t] += x;
        __syncthreads();
    }
    int excl = sh[t] - tsum;
    if (base + 0 < M) offs[base + 0] = excl;
    excl += v0;
    if (base + 1 < M) offs[base + 1] = excl;
    excl += v1;
    if (base + 2 < M) offs[base + 2] = excl;
    excl += v2;
    if (base + 3 < M) offs[base + 3] = excl;
    if (t == 255) bsum[blockIdx.x] = sh[255];
}

__global__ void scan2(int* __restrict__ bsum, int NB) {
    __shared__ int sh[256];
    int t = threadIdx.x;
    int v = (t < NB) ? bsum[t] : 0;
    sh[t] = v;
    __syncthreads();
    for (int off = 1; off < 256; off <<= 1) {
        int x = (t >= off) ? sh[t - off] : 0;
        __syncthreads();
        sh[t] += x;
        __syncthreads();
    }
    if (t < NB) bsum[t] = sh[t] - v;
}

__global__ void scan3(int* __restrict__ offs, const int* __restrict__ bsum,
                      int* __restrict__ cur, int M) {
    int i = blockIdx.x * blockDim.x + threadIdx.x;
    if (i < M) {
        int o = offs[i] + bsum[i >> 10];
        offs[i] = o;
        cur[i] = o;
    }
}

__global__ void fill_both(const int* __restrict__ src_e,
                          const int* __restrict__ dst_e,
                          const int* __restrict__ et,
                          const int* __restrict__ src_j,
                          const int* __restrict__ dst_j,
                          const float* __restrict__ ew,
                          int* __restrict__ cur, int2* __restrict__ pairs,
                          int E, int EJ, int N) {
    int i = blockIdx.x * blockDim.x + threadIdx.x;
    if (i < E) {
        int p = atomicAdd(&cur[dst_e[i]], 1);
        pairs[p] = make_int2(src_e[i], et[i]);
    } else if (i < E + EJ) {
        int e = i - E;
        int p = atomicAdd(&cur[N + dst_j[e]], 1);
        pairs[p] = make_int2(src_j[e], __float_as_int(ew[e]));
    }
}

// ===========================================================================
// Weight pack into MFMA B-fragment lane order (bf16), both layers.
// Stacked K: rows 0..127 = W (agg path), 128..255 = Wl (x path).
// ===========================================================================
__global__ void pack_w(const float* __restrict__ W1, const float* __restrict__ Wl1,
                       const float* __restrict__ W2, const float* __restrict__ Wl2,
                       short* __restrict__ B1, short* __restrict__ B2) {
    int lane = threadIdx.x;          // 64
    int tile = blockIdx.x & 63;      // tn = tile>>3, tk = tile&7
    const float* W  = (blockIdx.x < 64) ? W1 : W2;
    const float* Wl = (blockIdx.x < 64) ? Wl1 : Wl2;
    short* Bpk      = (blockIdx.x < 64) ? B1 : B2;
    int tn = tile >> 3, tk = tile & 7;
    int n = tn * 16 + (lane & 15);
    int k0 = tk * 32 + (lane >> 4) * 8;
    short* o = Bpk + ((size_t)tile * 64 + lane) * 8;
#pragma unroll
    for (int j = 0; j < 8; j++) {
        int k = k0 + j;
        float f = (k < D) ? W[(size_t)k * D + n] : Wl[(size_t)(k - D) * D + n];
        o[j] = f2bf(f);
    }
}

// emb -> Abf1 x-half (bf16); also change -> out passthrough copy.
__global__ void cvt_emb_copy(const float* __restrict__ emb,
                             const float* __restrict__ change,
                             short* __restrict__ Abf,
                             float* __restrict__ out, int N) {
    int i = blockIdx.x * blockDim.x + threadIdx.x;   // one thread per 4 elems
    int row = i >> 5;
    int c4 = (i & 31) * 4;
    if (row >= N) return;
    float4 v = *(const float4*)(emb + (size_t)row * D + c4);
    short4 o;
    o.x = f2bf(v.x); o.y = f2bf(v.y); o.z = f2bf(v.z); o.w = f2bf(v.w);
    *(short4*)(Abf + (size_t)row * 256 + 128 + c4) = o;
    float4 ch = *(const float4*)(change + (size_t)row * D + c4);
    *(float4*)(out + (size_t)row * D + c4) = ch;
}

// ===========================================================================
// Layer-1 gather: one wave per node; reads bf16 x rows from Abf x-half,
// fp32 rel (L1-resident); writes bf16 agg into Abf agg-half (cols 0..127).
// ===========================================================================
__global__ void gather_conv(short* __restrict__ Abf,
                            const float* __restrict__ rel,
                            const int* __restrict__ offs,
                            const int* __restrict__ cnt,
                            const int2* __restrict__ pairs, int N) {
    int node = blockIdx.x * 4 + (threadIdx.x >> 6);
    if (node >= N) return;
    int c = (threadIdx.x & 63) * 2;
    int beg = offs[node], num = cnt[node];
    float2 acc = make_float2(0.f, 0.f);
    for (int i = 0; i < num; i++) {
        int2 pe = pairs[beg + i];
        ushort2 xv = *(const ushort2*)(Abf + (size_t)pe.x * 256 + 128 + c);
        float2 rv = *(const float2*)(rel + (size_t)pe.y * D + c);
        acc.x += bf2f(xv.x) * rv.x;
        acc.y += bf2f(xv.y) * rv.y;
    }
    float dinv = 1.0f / fmaxf((float)num, 1.0f);
    short2 o;
    o.x = f2bf(acc.x * dinv);
    o.y = f2bf(acc.y * dinv);
    *(short2*)(Abf + (size_t)node * 256 + c) = o;
}

// ===========================================================================
// Phase-2 gathers merged: nodes [0,N) = layer-2 conv on Abf2 (h1 bf16);
// nodes [N,2N) = jump diffusion from Abf1 x-half (emb bf16) -> dch fp32.
// ===========================================================================
__global__ void gather_phase2(short* __restrict__ Abf2,
                              const short* __restrict__ Abf1,
                              const float* __restrict__ rel,
                              const float* __restrict__ jwp,
                              const int* __restrict__ offs,
                              const int* __restrict__ cnt,
                              const int2* __restrict__ pairs,
                              float* __restrict__ dch, int N) {
    int g = blockIdx.x * 4 + (threadIdx.x >> 6);
    int c = (threadIdx.x & 63) * 2;
    if (g < N) {
        int beg = offs[g], num = cnt[g];
        float2 acc = make_float2(0.f, 0.f);
        for (int i = 0; i < num; i++) {
            int2 pe = pairs[beg + i];
            ushort2 xv = *(const ushort2*)(Abf2 + (size_t)pe.x * 256 + 128 + c);
            float2 rv = *(const float2*)(rel + (size_t)pe.y * D + c);
            acc.x += bf2f(xv.x) * rv.x;
            acc.y += bf2f(xv.y) * rv.y;
        }
        float dinv = 1.0f / fmaxf((float)num, 1.0f);
        short2 o;
        o.x = f2bf(acc.x * dinv);
        o.y = f2bf(acc.y * dinv);
        *(short2*)(Abf2 + (size_t)g * 256 + c) = o;
    } else if (g < 2 * N) {
        int node = g - N;
        int beg = offs[N + node], num = cnt[N + node];
        float2 acc = make_float2(0.f, 0.f);
        for (int i = 0; i < num; i++) {
            int2 pe = pairs[beg + i];
            float w = __int_as_float(pe.y);
            ushort2 xv = *(const ushort2*)(Abf1 + (size_t)pe.x * 256 + 128 + c);
            acc.x += w * bf2f(xv.x);
            acc.y += w * bf2f(xv.y);
        }
        float jw = jwp[0];
        *(float2*)(dch + (size_t)node * D + c) = make_float2(jw * acc.x, jw * acc.y);
    }
}

// ===========================================================================
// MFMA GEMM: C = Abf[N][256] @ Bpk(256x128); o = bf16(x) + res*tanh(C).
// Layer 1: o -> outb x-half (bf16).  Layer 2: o + addin -> outf (fp32).
// Block: 256 thr = 4 waves, tile 64 rows x 128 cols; no LDS, no barriers.
// ===========================================================================
__launch_bounds__(256)
__global__ void mfma_gemm(const short* __restrict__ Abf,
                          const short* __restrict__ Bpk,
                          const float* __restrict__ resp,
                          short* __restrict__ outb,        // nullable
                          const float* __restrict__ addin, // nullable
                          float* __restrict__ outf,        // nullable
                          int N) {
    int w = threadIdx.x >> 6;
    int lane = threadIdx.x & 63;
    int rb = (w & 1) * 32;
    int cb = (w >> 1) * 64;
    int row0 = blockIdx.x * 64;
    int m = lane & 15, quad = lane >> 4;

    f32x4 acc[2][4];
#pragma unroll
    for (int rt = 0; rt < 2; rt++)
#pragma unroll
        for (int ct = 0; ct < 4; ct++) acc[rt][ct] = (f32x4)(0.f);

    const short* arow0 = Abf + (size_t)(row0 + rb + m) * 256 + quad * 8;
    const short* arow1 = arow0 + 16 * 256;
    const short* bbase = Bpk + (((size_t)(cb >> 4)) * 8 * 64 + lane) * 8;

#pragma unroll
    for (int kt = 0; kt < 8; kt++) {
        short8v a0 = *(const short8v*)(arow0 + kt * 32);
        short8v a1 = *(const short8v*)(arow1 + kt * 32);
        short8v b[4];
#pragma unroll
        for (int ct = 0; ct < 4; ct++)
            b[ct] = *(const short8v*)(bbase + ((size_t)(ct * 8 + kt)) * 64 * 8);
#pragma unroll
        for (int ct = 0; ct < 4; ct++) {
            acc[0][ct] = __builtin_amdgcn_mfma_f32_16x16x32_bf16(a0, b[ct],
                                                                 acc[0][ct], 0, 0, 0);
            acc[1][ct] = __builtin_amdgcn_mfma_f32_16x16x32_bf16(a1, b[ct],
                                                                 acc[1][ct], 0, 0, 0);
        }
    }

    float res = resp[0];
#pragma unroll
    for (int rt = 0; rt < 2; rt++) {
#pragma unroll
        for (int ct = 0; ct < 4; ct++) {
            int colg = cb + ct * 16 + m;
#pragma unroll
            for (int r = 0; r < 4; r++) {
                int rowg = row0 + rb + rt * 16 + quad * 4 + r;
                if (rowg >= N) continue;
                float xr = bf2f((unsigned short)Abf[(size_t)rowg * 256 + 128 + colg]);
                float o = xr + res * tanhf(acc[rt][ct][r]);
                if (outb != nullptr) {
                    outb[(size_t)rowg * 256 + 128 + colg] = f2bf(o);
                } else {
                    size_t idx = (size_t)rowg * D + colg;
                    outf[idx] = o + addin[idx];
                }
            }
        }
    }
}

extern "C" void kernel_launch(void* const* d_in, const int* in_sizes, int n_in,
                              void* d_out, int out_size, void* d_ws, size_t ws_size,
                              hipStream_t stream) {
    const float* emb    = (const float*)d_in[0];
    const float* change = (const float*)d_in[1];
    const float* W1     = (const float*)d_in[2];
    const float* Wl1    = (const float*)d_in[3];
    const float* rel1   = (const float*)d_in[4];
    const float* W2     = (const float*)d_in[5];
    const float* Wl2    = (const float*)d_in[6];
    const float* rel2   = (const float*)d_in[7];
    const float* res    = (const float*)d_in[8];
    const float* jw     = (const float*)d_in[9];
    const float* ewj    = (const float*)d_in[10];
    const int*   eidx   = (const int*)d_in[11];
    const int*   etype  = (const int*)d_in[12];
    const int*   ejmp   = (const int*)d_in[13];

    const int ND = in_sizes[0];
    const int N  = ND / D;
    const int E  = in_sizes[12];
    const int EJ = in_sizes[10];
    const int NP = ((N + 63) / 64) * 64;     // row-padded for 64-row GEMM tiles
    const int M  = 2 * N;                    // concatenated CSR counters

    float* out = (float*)d_out;          // change passthrough
    float* dch = out + (size_t)ND;       // dchange

    // workspace layout (16B-aligned chunks)
    char* w = (char*)d_ws;
    short* Abf1  = (short*)w;                  w += (size_t)NP * 256 * 2;
    short* Abf2  = (short*)w;                  w += (size_t)NP * 256 * 2;
    short* Bpk1  = (short*)w;                  w += (size_t)64 * 64 * 8 * 2;
    short* Bpk2  = (short*)w;                  w += (size_t)64 * 64 * 8 * 2;
    int* cnt     = (int*)w;                    w += (size_t)M * 4;
    int* offs    = (int*)w;                    w += (size_t)M * 4;
    int* cur     = (int*)w;                    w += (size_t)M * 4;
    int* bsum    = (int*)w;                    w += 256 * 4;
    int2* pairs  = (int2*)w;                   w += (size_t)(E + EJ) * 8;

    const int T = 256;
    const int NB2 = (M + 1023) / 1024;
    const int EB  = (E + EJ + T - 1) / T;

    hipMemsetAsync(cnt, 0, (size_t)M * sizeof(int), stream);

    // ---- concatenated CSR build (conv + jump) ----
    hist_both<<<EB, T, 0, stream>>>(eidx + E, ejmp + EJ, cnt, E, EJ, N);
    scan1<<<NB2, 256, 0, stream>>>(cnt, offs, bsum, M);
    scan2<<<1, 256, 0, stream>>>(bsum, NB2);
    scan3<<<(M + T - 1) / T, T, 0, stream>>>(offs, bsum, cur, M);
    fill_both<<<EB, T, 0, stream>>>(eidx, eidx + E, etype, ejmp, ejmp + EJ, ewj,
                                    cur, pairs, E, EJ, N);

    // ---- weight packs (both layers) ----
    pack_w<<<128, 64, 0, stream>>>(W1, Wl1, W2, Wl2, Bpk1, Bpk2);

    // ---- emb -> bf16, change -> out ----
    cvt_emb_copy<<<(N * 32 + T - 1) / T, T, 0, stream>>>(emb, change, Abf1, out, N);

    int gatherB  = (N + 3) / 4;
    int gather2B = (M + 3) / 4;
    int gemmB    = NP / 64;

    // ---- layer 1: gather + GEMM (h1 -> Abf2 x-half bf16) ----
    gather_conv<<<gatherB, 256, 0, stream>>>(Abf1, rel1, offs, cnt, pairs, N);
    mfma_gemm<<<gemmB, 256, 0, stream>>>(Abf1, Bpk1, res, Abf2, nullptr, nullptr, N);

    // ---- layer-2 conv gather + jump gather (merged) ----
    gather_phase2<<<gather2B, 256, 0, stream>>>(Abf2, Abf1, rel2, jw, offs, cnt,
                                                pairs, dch, N);

    // ---- layer 2 GEMM: dch = h1 + res*tanh(...) + jump ----
    mfma_gemm<<<gemmB, 256, 0, stream>>>(Abf2, Bpk2, res, nullptr, dch, dch, N);
}